// Round 1
// baseline (375.975 us; speedup 1.0000x reference)
//
#include <hip/hip_runtime.h>

#define NROWS 16384
#define DIM   1024
#define QSCALE 32.0f            // fp4 pre-scale 2^5
#define E8M0S  0x7A7A7A7Au      // 122 -> 2^-5 in every byte (both operands)

typedef int    v4i    __attribute__((ext_vector_type(4)));
typedef int    v8i    __attribute__((ext_vector_type(8)));
typedef float  f32x16 __attribute__((ext_vector_type(16)));

__device__ __forceinline__ void glds16(const void* g, void* l) {
    __builtin_amdgcn_global_load_lds(
        (const __attribute__((address_space(1))) void*)g,
        (__attribute__((address_space(3))) void*)l,
        16, 0, 0);
}

__device__ __forceinline__ float fexp2(float x) {
#if __has_builtin(__builtin_amdgcn_exp2f)
    return __builtin_amdgcn_exp2f(x);
#else
    return exp2f(x);
#endif
}
__device__ __forceinline__ float flog2(float x) {
#if __has_builtin(__builtin_amdgcn_logf)
    return __builtin_amdgcn_logf(x);
#else
    return log2f(x);
#endif
}

// fp4 e2m1 round-to-nearest encode of y (|y| clipped to 6).
__device__ __forceinline__ unsigned fp4_nib(float y) {
    unsigned s = (__float_as_uint(y) >> 31) << 3;
    float a = fminf(fabsf(y), 6.0f);
    unsigned c = (unsigned)(a >= 0.25f) + (unsigned)(a >= 0.75f) +
                 (unsigned)(a >= 1.25f) + (unsigned)(a >= 1.75f) +
                 (unsigned)(a >= 2.5f)  + (unsigned)(a >= 3.5f)  +
                 (unsigned)(a >= 5.0f);
    return c | s;
}

// Wave-per-row, grid-stride. Lane-interleaved float4 loads: every load
// instruction is a fully-coalesced 1KB wave transaction. Lane j-th float4 is
// row element block (lane + 64j); its 4 nibbles pack into one ushort at the
// same index (little-endian nibble order matches memory order).
__global__ __launch_bounds__(256) void norm_fused(
    const float* __restrict__ img,
    const float* __restrict__ txt,
    unsigned char* __restrict__ imgQ,   // [NROWS][512] packed fp4
    unsigned char* __restrict__ txtQ,
    const float* __restrict__ lscale,
    const float* __restrict__ lbias,
    float* __restrict__ diagPart) {
    const int t    = threadIdx.x;
    const int lane = t & 63;
    const int wave = t >> 6;
    const int gw   = blockIdx.x * 4 + wave;   // 8192 waves total
    const float sc   = __expf(lscale[0]);
    const float bias = lbias[0];

    for (int row = gw; row < NROWS; row += 8192) {
        const float4* pi = (const float4*)(img + (size_t)row * DIM);
        const float4* pt = (const float4*)(txt + (size_t)row * DIM);
        float4 vi[4], vt[4];
        float ssi = 0.0f, sst = 0.0f, dot = 0.0f;
        #pragma unroll
        for (int j = 0; j < 4; ++j) {
            vi[j] = pi[lane + 64 * j];
            vt[j] = pt[lane + 64 * j];
            ssi += vi[j].x*vi[j].x + vi[j].y*vi[j].y + vi[j].z*vi[j].z + vi[j].w*vi[j].w;
            sst += vt[j].x*vt[j].x + vt[j].y*vt[j].y + vt[j].z*vt[j].z + vt[j].w*vt[j].w;
            dot += vi[j].x*vt[j].x + vi[j].y*vt[j].y + vi[j].z*vt[j].z + vi[j].w*vt[j].w;
        }
        #pragma unroll
        for (int off = 1; off < 64; off <<= 1) {
            ssi += __shfl_xor(ssi, off, 64);
            sst += __shfl_xor(sst, off, 64);
            dot += __shfl_xor(dot, off, 64);
        }
        const float ii = 1.0f / fmaxf(sqrtf(ssi), 1e-12f);
        const float it = 1.0f / fmaxf(sqrtf(sst), 1e-12f);
        if (lane == 0) diagPart[row] = -fmaf(sc, dot * ii * it, bias);

        const float qi = ii * QSCALE, qt = it * QSCALE;
        ushort* oi = (ushort*)(imgQ + (size_t)row * 512);
        ushort* ot = (ushort*)(txtQ + (size_t)row * 512);
        #pragma unroll
        for (int j = 0; j < 4; ++j) {
            unsigned p = fp4_nib(vi[j].x * qi)        | (fp4_nib(vi[j].y * qi) << 4) |
                         (fp4_nib(vi[j].z * qi) << 8) | (fp4_nib(vi[j].w * qi) << 12);
            unsigned q = fp4_nib(vt[j].x * qt)        | (fp4_nib(vt[j].y * qt) << 4) |
                         (fp4_nib(vt[j].z * qt) << 8) | (fp4_nib(vt[j].w * qt) << 12);
            oi[lane + 64 * j] = (ushort)p;
            ot[lane + 64 * j] = (ushort)q;
        }
    }
}

// MX-fp4 GEMM, 256x128 block tile, BK=256 elems (128B rows), 4 K-iters.
// 4 waves as 2x2; wave tile 128x64 = 4x2 of 32x32 -> 6 LDS b128 reads per
// 8 MFMA (0.75 KB/mfma vs 1.0 at 64x64).
//
// R-current change: DOUBLE-BUFFERED K-pipeline (T3-minimum recipe).
// Per iter: issue next tile's 12 glds16 FIRST, then ds_read+MFMA the
// current tile, then one __syncthreads() (vmcnt(0) hidden behind ~1200cy
// of compute). 96 KB LDS -> 1 block/CU; intra-block overlap of the three
// near-balanced pipes (MFMA ~1130cy/SIMD, LDS ~1150cy/CU, L2 loads)
// replaces the lost inter-block masking.
// LDS slot s of row r holds global chunk s ^ (r&7) ^ ((r>>4)&1) (R6's
// measured-zero-conflict scatter swizzle) — unchanged, only base alternates.
__global__ __launch_bounds__(256, 1) void siglip_gemm(
    const unsigned char* __restrict__ A,
    const unsigned char* __restrict__ B,
    const float* __restrict__ lscale,
    const float* __restrict__ lbias,
    float* __restrict__ gemmPart)
{
    __shared__ unsigned char sA[2][256 * 128];  // 2 x 32 KB
    __shared__ unsigned char sB[2][128 * 128];  // 2 x 16 KB
    __shared__ float wred[4];

    const int t    = threadIdx.x;
    const int lane = t & 63;
    const int wave = t >> 6;
    const int wr   = wave >> 1;     // A half (128 rows)
    const int wc   = wave & 1;      // B half (64 cols)
    const int r31  = lane & 31;
    const int h    = lane >> 5;     // k-half (32-elem MX block)
    const int xr   = (r31 & 7) ^ ((r31 >> 4) & 1);  // scatter row swizzle

    // grid 64 (M) x 128 (N); group-of-16 M-tiles for L2/L3 locality
    const int GRID_N = NROWS / 128;   // 128
    const int GM = 16;
    int b = blockIdx.x;
    int group = b / (GM * GRID_N);
    int ing   = b % (GM * GRID_N);
    int brow  = group * GM + (ing % GM);   // 0..63
    int bcol  = ing / GM;                  // 0..127

    const size_t aBase = (size_t)brow * 256;
    const size_t bBase = (size_t)bcol * 128;

    // Staging: glds16 = 1KB = 8 rows x 128B. lane -> (srow=l>>3, slot=l&7).
    // Wave w stages A slabs w*8..w*8+7 (64 rows) and B slabs w*4..w*4+3.
    const int srow = lane >> 3;
    const int c0   = (lane & 7) ^ srow;
    const int d01  = (c0 & 1) ? -16 : 16;   // toggle chunk bit0 when (row>>4)&1

    const unsigned char* aP = A + (size_t)(aBase + wave * 64 + srow) * 512 + c0 * 16;
    const unsigned char* bP = B + (size_t)(bBase + wave * 32 + srow) * 512 + c0 * 16;

    int rbA[4], rbB[2];
    #pragma unroll
    for (int i = 0; i < 4; ++i) rbA[i] = (wr * 128 + i * 32 + r31) * 128;
    #pragma unroll
    for (int i = 0; i < 2; ++i) rbB[i] = (wc * 64 + i * 32 + r31) * 128;

    f32x16 acc[4][2] = {};

    // ---- prologue: stage K-step 0 into buffer 0 ----
    {
        char* la = ((char*)sA[0]) + wave * 8192;
        char* lb = ((char*)sB[0]) + wave * 4096;
        #pragma unroll
        for (int j = 0; j < 8; ++j) {
            const int tog = ((j >> 1) & 1) ? d01 : 0;
            glds16(aP + j * 8 * 512 + tog, la + j * 1024);
        }
        #pragma unroll
        for (int j = 0; j < 4; ++j) {
            const int tog = ((j >> 1) & 1) ? d01 : 0;
            glds16(bP + j * 8 * 512 + tog, lb + j * 1024);
        }
    }
    __syncthreads();

    #pragma unroll
    for (int k = 0; k < 4; ++k) {
        const int cur = k & 1;

        // ---- issue next K-step's staging into the other buffer ----
        if (k < 3) {
            const unsigned char* aN = aP + (k + 1) * 128;
            const unsigned char* bN = bP + (k + 1) * 128;
            char* la = ((char*)sA[cur ^ 1]) + wave * 8192;
            char* lb = ((char*)sB[cur ^ 1]) + wave * 4096;
            #pragma unroll
            for (int j = 0; j < 8; ++j) {            // A slab j: rows j*8..j*8+7
                const int tog = ((j >> 1) & 1) ? d01 : 0;
                glds16(aN + j * 8 * 512 + tog, la + j * 1024);
            }
            #pragma unroll
            for (int j = 0; j < 4; ++j) {            // B slab j
                const int tog = ((j >> 1) & 1) ? d01 : 0;
                glds16(bN + j * 8 * 512 + tog, lb + j * 1024);
            }
        }

        // ---- compute current buffer ----
        #pragma unroll
        for (int ks = 0; ks < 4; ++ks) {
            const int s = ((ks * 2 + h) ^ xr) * 16;
            v8i af[4], bf[2];
            #pragma unroll
            for (int i = 0; i < 4; ++i) {
                v4i v = *(const v4i*)(sA[cur] + rbA[i] + s);
                af[i] = __builtin_shufflevector(v, v, 0, 1, 2, 3, -1, -1, -1, -1);
            }
            #pragma unroll
            for (int i = 0; i < 2; ++i) {
                v4i v = *(const v4i*)(sB[cur] + rbB[i] + s);
                bf[i] = __builtin_shufflevector(v, v, 0, 1, 2, 3, -1, -1, -1, -1);
            }
            #pragma unroll
            for (int mi = 0; mi < 4; ++mi)
                #pragma unroll
                for (int ni = 0; ni < 2; ++ni)
                    acc[mi][ni] = __builtin_amdgcn_mfma_scale_f32_32x32x64_f8f6f4(
                        af[mi], bf[ni], acc[mi][ni],
                        4, 4,                     // cbsz=fp4(e2m1), blgp=fp4
                        0, (int)E8M0S,
                        0, (int)E8M0S);
        }

        // waits vmcnt(0) (the 12 loads issued above, ~1200cy ago) + barrier
        __syncthreads();
    }

    // Epilogue: softplus(z) over all elements (label=-1 form); diagonal fixed
    // by -z_ii. Group-of-4 log trick (t <= ~31, 4-term product < 2^125: safe).
    const float l2e   = 1.44269504088896341f;
    const float scale = __expf(lscale[0]);
    const float aCo   = scale * l2e;
    const float bCo   = lbias[0] * l2e;
    float local = 0.0f;
    #pragma unroll
    for (int mi = 0; mi < 4; ++mi)
        #pragma unroll
        for (int ni = 0; ni < 2; ++ni)
            #pragma unroll
            for (int r = 0; r < 16; r += 4) {
                float e0 = fexp2(fmaf(aCo, acc[mi][ni][r + 0], bCo));
                float e1 = fexp2(fmaf(aCo, acc[mi][ni][r + 1], bCo));
                float e2 = fexp2(fmaf(aCo, acc[mi][ni][r + 2], bCo));
                float e3 = fexp2(fmaf(aCo, acc[mi][ni][r + 3], bCo));
                float p  = ((1.0f + e0) * (1.0f + e1)) *
                           ((1.0f + e2) * (1.0f + e3));
                local += flog2(p);
            }

    #pragma unroll
    for (int off = 32; off > 0; off >>= 1) local += __shfl_down(local, off, 64);
    if (lane == 0) wred[wave] = local;
    __syncthreads();
    if (t == 0)
        gemmPart[blockIdx.x] =
            (wred[0] + wred[1] + wred[2] + wred[3]) * 0.69314718055994531f;
}

// Sum 24576 partials (diagPart 16384 ++ gemmPart 8192, contiguous) -> loss.
__global__ __launch_bounds__(1024) void finalize_kernel(
    const float* __restrict__ parts, float* __restrict__ out) {
    __shared__ float wr[16];
    const int t    = threadIdx.x;
    const int lane = t & 63;
    const int wave = t >> 6;
    const float4* p4 = (const float4*)parts;   // 6144 float4
    float s = 0.0f;
    for (int i = t; i < 6144; i += 1024) {
        float4 v = p4[i];
        s += v.x + v.y + v.z + v.w;
    }
    #pragma unroll
    for (int off = 32; off > 0; off >>= 1) s += __shfl_down(s, off, 64);
    if (lane == 0) wr[wave] = s;
    __syncthreads();
    if (t == 0) {
        float tot = 0.0f;
        #pragma unroll
        for (int i = 0; i < 16; ++i) tot += wr[i];
        out[0] = tot / 268435456.0f;   // / N^2
    }
}

extern "C" void kernel_launch(void* const* d_in, const int* in_sizes, int n_in,
                              void* d_out, int out_size, void* d_ws, size_t ws_size,
                              hipStream_t stream) {
    const float* img    = (const float*)d_in[0];
    const float* txt    = (const float*)d_in[1];
    const float* lscale = (const float*)d_in[2];
    const float* lbias  = (const float*)d_in[3];
    float* out = (float*)d_out;

    char* ws = (char*)d_ws;
    unsigned char* imgQ = (unsigned char*)ws;                          // 8 MB
    unsigned char* txtQ = (unsigned char*)(ws + (size_t)NROWS * 512);  // 8 MB
    float* parts   = (float*)(ws + (size_t)2 * NROWS * 512);           // 24576 floats
    float* diagPart = parts;
    float* gemmPart = parts + NROWS;

    norm_fused<<<2048, 256, 0, stream>>>(img, txt, imgQ, txtQ, lscale, lbias, diagPart);
    siglip_gemm<<<dim3((NROWS / 256) * (NROWS / 128)), 256, 0, stream>>>(
        imgQ, txtQ, lscale, lbias, gemmPart);
    finalize_kernel<<<1, 1024, 0, stream>>>(parts, out);
}

// Round 2
// 311.987 us; speedup vs baseline: 1.2051x; 1.2051x over previous
//
#include <hip/hip_runtime.h>

#define NROWS 16384
#define DIM   1024
#define QSCALE 32.0f            // fp4 pre-scale 2^5
#define E8M0S  0x7A7A7A7Au      // 122 -> 2^-5 in every byte (both operands)

typedef int    v4i    __attribute__((ext_vector_type(4)));
typedef int    v8i    __attribute__((ext_vector_type(8)));
typedef float  f32x16 __attribute__((ext_vector_type(16)));

__device__ __forceinline__ void glds16(const void* g, void* l) {
    __builtin_amdgcn_global_load_lds(
        (const __attribute__((address_space(1))) void*)g,
        (__attribute__((address_space(3))) void*)l,
        16, 0, 0);
}

__device__ __forceinline__ float fexp2(float x) {
#if __has_builtin(__builtin_amdgcn_exp2f)
    return __builtin_amdgcn_exp2f(x);
#else
    return exp2f(x);
#endif
}
__device__ __forceinline__ float flog2(float x) {
#if __has_builtin(__builtin_amdgcn_logf)
    return __builtin_amdgcn_logf(x);
#else
    return log2f(x);
#endif
}

// fp4 e2m1 round-to-nearest encode of y (|y| clipped to 6).
__device__ __forceinline__ unsigned fp4_nib(float y) {
    unsigned s = (__float_as_uint(y) >> 31) << 3;
    float a = fminf(fabsf(y), 6.0f);
    unsigned c = (unsigned)(a >= 0.25f) + (unsigned)(a >= 0.75f) +
                 (unsigned)(a >= 1.25f) + (unsigned)(a >= 1.75f) +
                 (unsigned)(a >= 2.5f)  + (unsigned)(a >= 3.5f)  +
                 (unsigned)(a >= 5.0f);
    return c | s;
}

// Wave-per-row, grid-stride. Lane-interleaved float4 loads: every load
// instruction is a fully-coalesced 1KB wave transaction.
__global__ __launch_bounds__(256) void norm_fused(
    const float* __restrict__ img,
    const float* __restrict__ txt,
    unsigned char* __restrict__ imgQ,   // [NROWS][512] packed fp4
    unsigned char* __restrict__ txtQ,
    const float* __restrict__ lscale,
    const float* __restrict__ lbias,
    float* __restrict__ diagPart) {
    const int t    = threadIdx.x;
    const int lane = t & 63;
    const int wave = t >> 6;
    const int gw   = blockIdx.x * 4 + wave;   // 8192 waves total
    const float sc   = __expf(lscale[0]);
    const float bias = lbias[0];

    for (int row = gw; row < NROWS; row += 8192) {
        const float4* pi = (const float4*)(img + (size_t)row * DIM);
        const float4* pt = (const float4*)(txt + (size_t)row * DIM);
        float4 vi[4], vt[4];
        float ssi = 0.0f, sst = 0.0f, dot = 0.0f;
        #pragma unroll
        for (int j = 0; j < 4; ++j) {
            vi[j] = pi[lane + 64 * j];
            vt[j] = pt[lane + 64 * j];
            ssi += vi[j].x*vi[j].x + vi[j].y*vi[j].y + vi[j].z*vi[j].z + vi[j].w*vi[j].w;
            sst += vt[j].x*vt[j].x + vt[j].y*vt[j].y + vt[j].z*vt[j].z + vt[j].w*vt[j].w;
            dot += vi[j].x*vt[j].x + vi[j].y*vt[j].y + vi[j].z*vt[j].z + vi[j].w*vt[j].w;
        }
        #pragma unroll
        for (int off = 1; off < 64; off <<= 1) {
            ssi += __shfl_xor(ssi, off, 64);
            sst += __shfl_xor(sst, off, 64);
            dot += __shfl_xor(dot, off, 64);
        }
        const float ii = 1.0f / fmaxf(sqrtf(ssi), 1e-12f);
        const float it = 1.0f / fmaxf(sqrtf(sst), 1e-12f);
        if (lane == 0) diagPart[row] = -fmaf(sc, dot * ii * it, bias);

        const float qi = ii * QSCALE, qt = it * QSCALE;
        ushort* oi = (ushort*)(imgQ + (size_t)row * 512);
        ushort* ot = (ushort*)(txtQ + (size_t)row * 512);
        #pragma unroll
        for (int j = 0; j < 4; ++j) {
            unsigned p = fp4_nib(vi[j].x * qi)        | (fp4_nib(vi[j].y * qi) << 4) |
                         (fp4_nib(vi[j].z * qi) << 8) | (fp4_nib(vi[j].w * qi) << 12);
            unsigned q = fp4_nib(vt[j].x * qt)        | (fp4_nib(vt[j].y * qt) << 4) |
                         (fp4_nib(vt[j].z * qt) << 8) | (fp4_nib(vt[j].w * qt) << 12);
            oi[lane + 64 * j] = (ushort)p;
            ot[lane + 64 * j] = (ushort)q;
        }
    }
}

// MX-fp4 GEMM, 256x256 block tile, 512 threads (8 waves as 2x4), BK=256
// elems (128B rows), 4 K-iters, double-buffered LDS (128 KB -> 1 block/CU,
// but 2 waves/SIMD for latency hiding — R1's 1-wave/SIMD was the failure).
//
// Per K-step phase order (defeats any glds->ds_read alias-hazard wait):
//   1. ds_read ALL 24 fragments of buf[cur] into v4i regs
//   2. issue 8 glds16 staging next K-tile into buf[cur^1]
//   3. 32 MFMA (glds L2 latency ~1100cy hides under ~2266cy MFMA phase)
//   4. __syncthreads() (its vmcnt(0) drain settles the staging)
// LDS slot s of row r holds global chunk s ^ (r&7) ^ ((r>>4)&1) (measured
// zero-conflict scatter swizzle, unchanged).
__global__ __launch_bounds__(512, 2) void siglip_gemm(
    const unsigned char* __restrict__ A,
    const unsigned char* __restrict__ B,
    const float* __restrict__ lscale,
    const float* __restrict__ lbias,
    float* __restrict__ gemmPart)
{
    __shared__ unsigned char sA[2][256 * 128];  // 2 x 32 KB
    __shared__ unsigned char sB[2][256 * 128];  // 2 x 32 KB
    __shared__ float wred[8];

    const int t    = threadIdx.x;
    const int lane = t & 63;
    const int wave = t >> 6;        // 0..7
    const int wr   = wave >> 2;     // 0..1 : A half (128 rows)
    const int wc   = wave & 3;      // 0..3 : B quarter (64 cols)
    const int r31  = lane & 31;
    const int h    = lane >> 5;     // k-half (32-elem MX block)
    const int xr   = (r31 & 7) ^ ((r31 >> 4) & 1);  // scatter row swizzle

    // grid 64 (M) x 64 (N); group-of-16 M-tiles for L2/L3 locality
    const int GRID_N = NROWS / 256;   // 64
    const int GM = 16;
    int b = blockIdx.x;
    int group = b / (GM * GRID_N);
    int ing   = b % (GM * GRID_N);
    int brow  = group * GM + (ing % GM);   // 0..63
    int bcol  = ing / GM;                  // 0..63

    const size_t aBase = (size_t)brow * 256;
    const size_t bBase = (size_t)bcol * 256;

    // Staging: glds16 = 1KB = 8 rows x 128B. lane -> (srow=l>>3, slot=l&7).
    // Wave w stages A rows [w*32, w*32+32) = 4 slabs; same for B.
    const int srow = lane >> 3;
    const int c0   = (lane & 7) ^ srow;
    const int d01  = (c0 & 1) ? -16 : 16;   // toggle chunk bit0 when (row>>4)&1

    const unsigned char* aP = A + (size_t)(aBase + wave * 32 + srow) * 512 + c0 * 16;
    const unsigned char* bP = B + (size_t)(bBase + wave * 32 + srow) * 512 + c0 * 16;

    int rbA[4], rbB[2];
    #pragma unroll
    for (int i = 0; i < 4; ++i) rbA[i] = (wr * 128 + i * 32 + r31) * 128;
    #pragma unroll
    for (int i = 0; i < 2; ++i) rbB[i] = (wc * 64 + i * 32 + r31) * 128;

    f32x16 acc[4][2] = {};

    // ---- prologue: stage K-step 0 into buffer 0 ----
    {
        char* la = ((char*)sA[0]) + wave * 4096;
        char* lb = ((char*)sB[0]) + wave * 4096;
        #pragma unroll
        for (int j = 0; j < 4; ++j) {
            const int tog = ((j >> 1) & 1) ? d01 : 0;   // bit4 of row = (j>>1)&1
            glds16(aP + j * 8 * 512 + tog, la + j * 1024);
            glds16(bP + j * 8 * 512 + tog, lb + j * 1024);
        }
    }
    __syncthreads();

    #pragma unroll
    for (int k = 0; k < 4; ++k) {
        const int cur = k & 1;      // compile-time under full unroll

        // ---- phase 1: read ALL fragments of current buffer into regs ----
        v4i af[4][4], bf[4][2];     // [ks][mi] / [ks][ni] — all indices static
        #pragma unroll
        for (int ks = 0; ks < 4; ++ks) {
            const int s = ((ks * 2 + h) ^ xr) * 16;
            #pragma unroll
            for (int i = 0; i < 4; ++i)
                af[ks][i] = *(const v4i*)(sA[cur] + rbA[i] + s);
            #pragma unroll
            for (int n = 0; n < 2; ++n)
                bf[ks][n] = *(const v4i*)(sB[cur] + rbB[n] + s);
        }

        // ---- phase 2: issue next K-step's staging into other buffer ----
        if (k < 3) {
            const unsigned char* aN = aP + (k + 1) * 128;
            const unsigned char* bN = bP + (k + 1) * 128;
            char* la = ((char*)sA[cur ^ 1]) + wave * 4096;
            char* lb = ((char*)sB[cur ^ 1]) + wave * 4096;
            #pragma unroll
            for (int j = 0; j < 4; ++j) {
                const int tog = ((j >> 1) & 1) ? d01 : 0;
                glds16(aN + j * 8 * 512 + tog, la + j * 1024);
                glds16(bN + j * 8 * 512 + tog, lb + j * 1024);
            }
        }

        // ---- phase 3: MFMA cluster (pure reg; glds drains underneath) ----
        #pragma unroll
        for (int ks = 0; ks < 4; ++ks) {
            #pragma unroll
            for (int mi = 0; mi < 4; ++mi) {
                v8i a8 = __builtin_shufflevector(af[ks][mi], af[ks][mi],
                                                 0, 1, 2, 3, -1, -1, -1, -1);
                #pragma unroll
                for (int ni = 0; ni < 2; ++ni) {
                    v8i b8 = __builtin_shufflevector(bf[ks][ni], bf[ks][ni],
                                                     0, 1, 2, 3, -1, -1, -1, -1);
                    acc[mi][ni] = __builtin_amdgcn_mfma_scale_f32_32x32x64_f8f6f4(
                        a8, b8, acc[mi][ni],
                        4, 4,                     // cbsz=fp4(e2m1), blgp=fp4
                        0, (int)E8M0S,
                        0, (int)E8M0S);
                }
            }
        }

        // ---- phase 4: barrier (drains staging vmcnt + syncs buffers) ----
        __syncthreads();
    }

    // Epilogue: softplus(z) over all elements (label=-1 form); diagonal fixed
    // by -z_ii. Group-of-4 log trick (t <= ~31, 4-term product < 2^125: safe).
    const float l2e   = 1.44269504088896341f;
    const float scale = __expf(lscale[0]);
    const float aCo   = scale * l2e;
    const float bCo   = lbias[0] * l2e;
    float local = 0.0f;
    #pragma unroll
    for (int mi = 0; mi < 4; ++mi)
        #pragma unroll
        for (int ni = 0; ni < 2; ++ni)
            #pragma unroll
            for (int r = 0; r < 16; r += 4) {
                float e0 = fexp2(fmaf(aCo, acc[mi][ni][r + 0], bCo));
                float e1 = fexp2(fmaf(aCo, acc[mi][ni][r + 1], bCo));
                float e2 = fexp2(fmaf(aCo, acc[mi][ni][r + 2], bCo));
                float e3 = fexp2(fmaf(aCo, acc[mi][ni][r + 3], bCo));
                float p  = ((1.0f + e0) * (1.0f + e1)) *
                           ((1.0f + e2) * (1.0f + e3));
                local += flog2(p);
            }

    #pragma unroll
    for (int off = 32; off > 0; off >>= 1) local += __shfl_down(local, off, 64);
    if (lane == 0) wred[wave] = local;
    __syncthreads();
    if (t == 0) {
        float tot = 0.0f;
        #pragma unroll
        for (int i = 0; i < 8; ++i) tot += wred[i];
        gemmPart[blockIdx.x] = tot * 0.69314718055994531f;
    }
}

// Sum 20480 partials (diagPart 16384 ++ gemmPart 4096, contiguous) -> loss.
__global__ __launch_bounds__(1024) void finalize_kernel(
    const float* __restrict__ parts, float* __restrict__ out) {
    __shared__ float wr[16];
    const int t    = threadIdx.x;
    const int lane = t & 63;
    const int wave = t >> 6;
    const float4* p4 = (const float4*)parts;   // 5120 float4
    float s = 0.0f;
    for (int i = t; i < 5120; i += 1024) {
        float4 v = p4[i];
        s += v.x + v.y + v.z + v.w;
    }
    #pragma unroll
    for (int off = 32; off > 0; off >>= 1) s += __shfl_down(s, off, 64);
    if (lane == 0) wr[wave] = s;
    __syncthreads();
    if (t == 0) {
        float tot = 0.0f;
        #pragma unroll
        for (int i = 0; i < 16; ++i) tot += wr[i];
        out[0] = tot / 268435456.0f;   // / N^2
    }
}

extern "C" void kernel_launch(void* const* d_in, const int* in_sizes, int n_in,
                              void* d_out, int out_size, void* d_ws, size_t ws_size,
                              hipStream_t stream) {
    const float* img    = (const float*)d_in[0];
    const float* txt    = (const float*)d_in[1];
    const float* lscale = (const float*)d_in[2];
    const float* lbias  = (const float*)d_in[3];
    float* out = (float*)d_out;

    char* ws = (char*)d_ws;
    unsigned char* imgQ = (unsigned char*)ws;                          // 8 MB
    unsigned char* txtQ = (unsigned char*)(ws + (size_t)NROWS * 512);  // 8 MB
    float* parts   = (float*)(ws + (size_t)2 * NROWS * 512);           // 20480 floats
    float* diagPart = parts;
    float* gemmPart = parts + NROWS;

    norm_fused<<<2048, 256, 0, stream>>>(img, txt, imgQ, txtQ, lscale, lbias, diagPart);
    siglip_gemm<<<dim3((NROWS / 256) * (NROWS / 256)), 512, 0, stream>>>(
        imgQ, txtQ, lscale, lbias, gemmPart);
    finalize_kernel<<<1, 1024, 0, stream>>>(parts, out);
}